// Round 1
// baseline (340.176 us; speedup 1.0000x reference)
//
#include <hip/hip_runtime.h>
#include <math.h>

#define T_IN 2048
#define TP   2051   // T+3 conv output length
#define F    256
#define H    384
#define CH   64
#define NC   33     // ceil(TP/CH)

// ---------- K1: conv1d (kernel=4, pad 3/3) -> xp (TP x F) ----------
__global__ void k1_conv(const float* __restrict__ x, const float* __restrict__ cw,
                        const float* __restrict__ cb, float* __restrict__ xp) {
    int t = blockIdx.x;
    int f = threadIdx.x;
    float w0 = cw[0], w1 = cw[1], w2 = cw[2], w3 = cw[3];
    float acc = cb[0];
    int i0 = t - 3;
    if (i0 + 0 >= 0 && i0 + 0 < T_IN) acc = fmaf(w0, x[(i0 + 0) * F + f], acc);
    if (i0 + 1 >= 0 && i0 + 1 < T_IN) acc = fmaf(w1, x[(i0 + 1) * F + f], acc);
    if (i0 + 2 >= 0 && i0 + 2 < T_IN) acc = fmaf(w2, x[(i0 + 2) * F + f], acc);
    if (i0 + 3 >= 0 && i0 + 3 < T_IN) acc = fmaf(w3, x[(i0 + 3) * F + f], acc);
    xp[t * F + f] = acc;
}

// ---------- K2: fused k/i/f projections over all t ----------
// zk = (xp@Wk^T + bk) / sqrt(H); ai = xp@Wi^T + bi (log i); lf = logsigmoid(xp@Wf^T + bf)
__global__ __launch_bounds__(256) void k2_proj(
    const float* __restrict__ xp,
    const float* __restrict__ Wk, const float* __restrict__ bk,
    const float* __restrict__ Wi, const float* __restrict__ bi,
    const float* __restrict__ Wf, const float* __restrict__ bf,
    float* __restrict__ zk, float* __restrict__ ai, float* __restrict__ lf) {
    __shared__ float xpt[16 * 260];   // 16 t-rows, stride 260 (16B-aligned rows, conflict-safe)
    int tid = threadIdx.x;
    int t0 = blockIdx.x * 16;
    int b0 = blockIdx.y * 192;
    for (int i = tid; i < 16 * 256; i += 256) {
        int r = i >> 8, c = i & 255;
        int t = t0 + r;
        xpt[r * 260 + c] = (t < TP) ? xp[t * 256 + c] : 0.0f;
    }
    __syncthreads();
    int tx = tid & 15, ty = tid >> 4;
    int t = t0 + tx;
    const float4* xrow = (const float4*)(xpt + tx * 260);
    for (int j = 0; j < 12; ++j) {
        int b = b0 + j * 16 + ty;
        const float4* wk = (const float4*)(Wk + b * 256);
        const float4* wi = (const float4*)(Wi + b * 256);
        const float4* wf = (const float4*)(Wf + b * 256);
        float4 ak = {0, 0, 0, 0}, av = {0, 0, 0, 0}, af = {0, 0, 0, 0};
        for (int f4 = 0; f4 < 64; ++f4) {
            float4 xv = xrow[f4];
            float4 k4 = wk[f4];
            float4 i4 = wi[f4];
            float4 fv = wf[f4];
            ak.x = fmaf(xv.x, k4.x, ak.x); ak.y = fmaf(xv.y, k4.y, ak.y);
            ak.z = fmaf(xv.z, k4.z, ak.z); ak.w = fmaf(xv.w, k4.w, ak.w);
            av.x = fmaf(xv.x, i4.x, av.x); av.y = fmaf(xv.y, i4.y, av.y);
            av.z = fmaf(xv.z, i4.z, av.z); av.w = fmaf(xv.w, i4.w, av.w);
            af.x = fmaf(xv.x, fv.x, af.x); af.y = fmaf(xv.y, fv.y, af.y);
            af.z = fmaf(xv.z, fv.z, af.z); af.w = fmaf(xv.w, fv.w, af.w);
        }
        if (t < TP) {
            float sk = (ak.x + ak.y) + (ak.z + ak.w);
            float si = (av.x + av.y) + (av.z + av.w);
            float sf = (af.x + af.y) + (af.z + af.w);
            zk[t * H + b] = (sk + bk[b]) * 0.05103103630798287f;  // 1/sqrt(384)
            ai[t * H + b] = si + bi[b];
            float zf = sf + bf[b];
            // log(sigmoid(zf)), numerically stable both sides
            lf[t * H + b] = (zf >= 0.0f) ? -log1pf(__expf(-zf)) : zf - log1pf(__expf(zf));
        }
    }
}

// ---------- K2b: q and o at the final timestep only ----------
__global__ void k2b_qo(const float* __restrict__ xp,
                       const float* __restrict__ Wq, const float* __restrict__ bq,
                       const float* __restrict__ Wo, const float* __restrict__ bo,
                       float* __restrict__ q, float* __restrict__ o) {
    __shared__ float xl[256];
    int tid = threadIdx.x;  // 384 threads
    if (tid < 256) xl[tid] = xp[(TP - 1) * 256 + tid];
    __syncthreads();
    float aq = 0.0f, ao = 0.0f;
    const float* wq = Wq + tid * 256;
    const float* wo = Wo + tid * 256;
    for (int f = 0; f < 256; ++f) {
        float xv = xl[f];
        aq = fmaf(xv, wq[f], aq);
        ao = fmaf(xv, wo[f], ao);
    }
    q[tid] = aq + bq[tid];
    float zo = ao + bo[tid];
    o[tid] = 1.0f / (1.0f + __expf(-zo));
}

// ---------- K3a: per-chunk sums of lf over t ----------
__global__ void k3a_chunksum(const float* __restrict__ lf, float* __restrict__ cs) {
    int c = blockIdx.x, b = threadIdx.x;  // 384 threads
    int ts = c * CH;
    int te = (ts + CH < TP) ? ts + CH : TP;
    float s = 0.0f;
    for (int t = ts; t < te; ++t) s += lf[t * H + b];
    cs[c * H + b] = s;
}

// ---------- K3b: reverse exclusive scan over chunks ----------
__global__ void k3b_scan(const float* __restrict__ cs, float* __restrict__ co) {
    int b = threadIdx.x;  // 384 threads
    float L = 0.0f;
    for (int c = NC - 1; c >= 0; --c) {
        co[c * H + b] = L;
        L += cs[c * H + b];
    }
}

// ---------- K3c: w_t[b] = exp(ai + L_t)*zk*q[b], in-place over ai ----------
__global__ void k3c_w(float* aiw,                       // in: ai (log i), out: w (same buffer)
                      const float* __restrict__ lf, const float* __restrict__ zk,
                      const float* __restrict__ co, const float* __restrict__ q) {
    int c = blockIdx.x, b = threadIdx.x;  // 384 threads
    int ts = c * CH;
    int te = (ts + CH < TP) ? ts + CH : TP;
    float L = co[c * H + b];
    float qb = q[b];
    for (int t = te - 1; t >= ts; --t) {
        int idx = t * H + b;
        float v = __expf(aiw[idx] + L) * zk[idx] * qb;
        float lfv = lf[idx];
        aiw[idx] = v;      // same-thread read-then-write: safe in place
        L += lfv;
    }
}

// ---------- K4: g_t = sum_b w_t[b] ----------
__global__ void k4_g(const float* __restrict__ w, float* __restrict__ g) {
    int t = blockIdx.x;
    int lane = threadIdx.x;  // 64 threads
    float s = 0.0f;
    for (int j = 0; j < 6; ++j) s += w[t * H + lane + j * 64];
    for (int off = 32; off; off >>= 1) s += __shfl_down(s, off, 64);
    if (lane == 0) g[t] = s;
}

// ---------- K5a: partial z[f] = sum_{t in chunk} g_t * xp[t,f] ----------
__global__ void k5a_zpart(const float* __restrict__ g, const float* __restrict__ xp,
                          float* __restrict__ zp) {
    int c = blockIdx.x, f = threadIdx.x;  // 256 threads
    int ts = c * CH;
    int te = (ts + CH < TP) ? ts + CH : TP;
    float acc = 0.0f;
    for (int t = ts; t < te; ++t) acc = fmaf(g[t], xp[t * 256 + f], acc);
    zp[c * 256 + f] = acc;
}

// ---------- K5b: z[f] = sum_c zp ----------
__global__ void k5b_z(const float* __restrict__ zp, float* __restrict__ z) {
    int f = threadIdx.x;  // 256 threads
    float acc = 0.0f;
    for (int c = 0; c < NC; ++c) acc += zp[c * 256 + f];
    z[f] = acc;
}

// ---------- K6: h[a] = o[a]*(Wv[a]·z + bv[a]*G)/max(|G|,1) ----------
__global__ void k6_out(const float* __restrict__ g, const float* __restrict__ z,
                       const float* __restrict__ Wv, const float* __restrict__ bv,
                       const float* __restrict__ o, float* __restrict__ out) {
    __shared__ float zl[256];
    __shared__ float red[6];
    int tid = threadIdx.x;  // 384 threads
    if (tid < 256) zl[tid] = z[tid];
    float gs = 0.0f;
    for (int t = tid; t < TP; t += 384) gs += g[t];
    for (int off = 32; off; off >>= 1) gs += __shfl_down(gs, off, 64);
    int wv = tid >> 6, lane = tid & 63;
    if (lane == 0) red[wv] = gs;
    __syncthreads();
    float G = ((red[0] + red[1]) + (red[2] + red[3])) + (red[4] + red[5]);
    float acc = bv[tid] * G;
    const float* wrow = Wv + tid * 256;
    for (int f = 0; f < 256; ++f) acc = fmaf(zl[f], wrow[f], acc);
    float den = fmaxf(fabsf(G), 1.0f);
    out[tid] = o[tid] * acc / den;
}

extern "C" void kernel_launch(void* const* d_in, const int* in_sizes, int n_in,
                              void* d_out, int out_size, void* d_ws, size_t ws_size,
                              hipStream_t stream) {
    const float* x  = (const float*)d_in[0];
    const float* Wq = (const float*)d_in[1];  const float* bq = (const float*)d_in[2];
    const float* Wk = (const float*)d_in[3];  const float* bk = (const float*)d_in[4];
    const float* Wv = (const float*)d_in[5];  const float* bv = (const float*)d_in[6];
    const float* Wi = (const float*)d_in[7];  const float* bi = (const float*)d_in[8];
    const float* Wf = (const float*)d_in[9];  const float* bf = (const float*)d_in[10];
    const float* Wo = (const float*)d_in[11]; const float* bo = (const float*)d_in[12];
    const float* cw = (const float*)d_in[13]; const float* cb = (const float*)d_in[14];
    float* out = (float*)d_out;

    float* ws = (float*)d_ws;
    // workspace layout (floats); total ~2.92M floats (~11.7 MB)
    float* xp  = ws;                       // TP*F   = 525056
    float* zk  = xp  + TP * F;             // TP*H   = 787584
    float* aiw = zk  + TP * H;             // TP*H   (ai, reused as w)
    float* lf  = aiw + TP * H;             // TP*H
    float* cs  = lf  + TP * H;             // NC*H   = 12672
    float* co  = cs  + NC * H;             // NC*H
    float* qv  = co  + NC * H;             // H
    float* ov  = qv  + H;                  // H
    float* g   = ov  + H;                  // TP (pad to 2052)
    float* zp  = g   + 2052;               // NC*F   = 8448
    float* z   = zp  + NC * F;             // F

    k1_conv<<<TP, 256, 0, stream>>>(x, cw, cb, xp);
    k2_proj<<<dim3(129, 2), 256, 0, stream>>>(xp, Wk, bk, Wi, bi, Wf, bf, zk, aiw, lf);
    k2b_qo<<<1, 384, 0, stream>>>(xp, Wq, bq, Wo, bo, qv, ov);
    k3a_chunksum<<<NC, 384, 0, stream>>>(lf, cs);
    k3b_scan<<<1, 384, 0, stream>>>(cs, co);
    k3c_w<<<NC, 384, 0, stream>>>(aiw, lf, zk, co, qv);
    k4_g<<<TP, 64, 0, stream>>>(aiw, g);
    k5a_zpart<<<NC, 256, 0, stream>>>(g, xp, zp);
    k5b_z<<<1, 256, 0, stream>>>(zp, z);
    k6_out<<<1, 384, 0, stream>>>(g, z, Wv, bv, ov, out);
}

// Round 2
// 275.636 us; speedup vs baseline: 1.2341x; 1.2341x over previous
//
#include <hip/hip_runtime.h>
#include <math.h>

#define T_IN 2048
#define TP   2051   // T+3 conv output length
#define F    256
#define H    384
#define CH   16     // chunk = k2's t-tile
#define NC   129    // ceil(TP/16)

// ---------- K1: conv1d (kernel=4, pad 3/3) -> xp (TP x F) ----------
__global__ void k1_conv(const float* __restrict__ x, const float* __restrict__ cw,
                        const float* __restrict__ cb, float* __restrict__ xp) {
    int t = blockIdx.x;
    int f = threadIdx.x;
    float w0 = cw[0], w1 = cw[1], w2 = cw[2], w3 = cw[3];
    float acc = cb[0];
    int i0 = t - 3;
    if (i0 + 0 >= 0 && i0 + 0 < T_IN) acc = fmaf(w0, x[(i0 + 0) * F + f], acc);
    if (i0 + 1 >= 0 && i0 + 1 < T_IN) acc = fmaf(w1, x[(i0 + 1) * F + f], acc);
    if (i0 + 2 >= 0 && i0 + 2 < T_IN) acc = fmaf(w2, x[(i0 + 2) * F + f], acc);
    if (i0 + 3 >= 0 && i0 + 3 < T_IN) acc = fmaf(w3, x[(i0 + 3) * F + f], acc);
    xp[t * F + f] = acc;
}

// ---------- K2: fused k/i/f projections + per-chunk lf sums ----------
// grid (129, 8): 16 t-rows x 48 b-cols per block.
// zk = (xp@Wk^T+bk)/sqrt(H); ai = xp@Wi^T+bi; lf = logsigmoid(xp@Wf^T+bf)
// cs[c][b] = sum over the 16-t chunk of lf  (k3a folded in via 16-lane shuffle)
__global__ __launch_bounds__(256) void k2_proj(
    const float* __restrict__ xp,
    const float* __restrict__ Wk, const float* __restrict__ bk,
    const float* __restrict__ Wi, const float* __restrict__ bi,
    const float* __restrict__ Wf, const float* __restrict__ bf,
    float* __restrict__ zk, float* __restrict__ ai, float* __restrict__ lf,
    float* __restrict__ cs) {
    __shared__ float xpt[16 * 260];   // 16 t-rows, stride 260
    int tid = threadIdx.x;
    int t0 = blockIdx.x * 16;
    int b0 = blockIdx.y * 48;
    for (int i = tid; i < 16 * 256; i += 256) {
        int r = i >> 8, c = i & 255;
        int t = t0 + r;
        xpt[r * 260 + c] = (t < TP) ? xp[t * 256 + c] : 0.0f;
    }
    __syncthreads();
    int tx = tid & 15, ty = tid >> 4;
    int t = t0 + tx;
    const float4* xrow = (const float4*)(xpt + tx * 260);
    for (int j = 0; j < 3; ++j) {
        int b = b0 + j * 16 + ty;
        const float4* wk = (const float4*)(Wk + b * 256);
        const float4* wi = (const float4*)(Wi + b * 256);
        const float4* wf = (const float4*)(Wf + b * 256);
        float4 ak = {0, 0, 0, 0}, av = {0, 0, 0, 0}, af = {0, 0, 0, 0};
        for (int f4 = 0; f4 < 64; ++f4) {
            float4 xv = xrow[f4];
            float4 k4 = wk[f4];
            float4 i4 = wi[f4];
            float4 fv = wf[f4];
            ak.x = fmaf(xv.x, k4.x, ak.x); ak.y = fmaf(xv.y, k4.y, ak.y);
            ak.z = fmaf(xv.z, k4.z, ak.z); ak.w = fmaf(xv.w, k4.w, ak.w);
            av.x = fmaf(xv.x, i4.x, av.x); av.y = fmaf(xv.y, i4.y, av.y);
            av.z = fmaf(xv.z, i4.z, av.z); av.w = fmaf(xv.w, i4.w, av.w);
            af.x = fmaf(xv.x, fv.x, af.x); af.y = fmaf(xv.y, fv.y, af.y);
            af.z = fmaf(xv.z, fv.z, af.z); af.w = fmaf(xv.w, fv.w, af.w);
        }
        float lfv = 0.0f;
        if (t < TP) {
            float sk = (ak.x + ak.y) + (ak.z + ak.w);
            float si = (av.x + av.y) + (av.z + av.w);
            float sf = (af.x + af.y) + (af.z + af.w);
            zk[t * H + b] = (sk + bk[b]) * 0.05103103630798287f;  // 1/sqrt(384)
            ai[t * H + b] = si + bi[b];
            float zf = sf + bf[b];
            lfv = (zf >= 0.0f) ? -log1pf(__expf(-zf)) : zf - log1pf(__expf(zf));
            lf[t * H + b] = lfv;
        }
        // reduce lfv over tx (lane bits 0-3) -> chunk sum for this b
        float s = lfv;
        s += __shfl_xor(s, 1, 64);
        s += __shfl_xor(s, 2, 64);
        s += __shfl_xor(s, 4, 64);
        s += __shfl_xor(s, 8, 64);
        if (tx == 0) cs[blockIdx.x * H + b] = s;
    }
}

// ---------- K2b: q and o at the final timestep only ----------
__global__ void k2b_qo(const float* __restrict__ xp,
                       const float* __restrict__ Wq, const float* __restrict__ bq,
                       const float* __restrict__ Wo, const float* __restrict__ bo,
                       float* __restrict__ q, float* __restrict__ o) {
    __shared__ float xl[256];
    int tid = threadIdx.x;  // 384 threads
    if (tid < 256) xl[tid] = xp[(TP - 1) * 256 + tid];
    __syncthreads();
    float aq = 0.0f, ao = 0.0f;
    const float4* wq = (const float4*)(Wq + tid * 256);
    const float4* wo = (const float4*)(Wo + tid * 256);
    const float4* xl4 = (const float4*)xl;
    for (int f = 0; f < 64; ++f) {
        float4 xv = xl4[f];
        float4 q4 = wq[f], o4 = wo[f];
        aq = fmaf(xv.x, q4.x, fmaf(xv.y, q4.y, fmaf(xv.z, q4.z, fmaf(xv.w, q4.w, aq))));
        ao = fmaf(xv.x, o4.x, fmaf(xv.y, o4.y, fmaf(xv.z, o4.z, fmaf(xv.w, o4.w, ao))));
    }
    q[tid] = aq + bq[tid];
    float zo = ao + bo[tid];
    o[tid] = 1.0f / (1.0f + __expf(-zo));
}

// ---------- K3b: reverse exclusive scan over chunk sums, in place ----------
__global__ void k3b_scan(float* cs) {
    int b = threadIdx.x;  // 384 threads
    float L = 0.0f;
    for (int c = NC - 1; c >= 0; --c) {
        float tmp = cs[c * H + b];
        cs[c * H + b] = L;     // exclusive-from-the-top
        L += tmp;
    }
}

// ---------- K3: fused w -> g_t -> (G chunk-partials, z chunk-partials) ----------
// grid NC blocks x 384 threads. Eliminates the w write + re-read and k4/k5a.
__global__ __launch_bounds__(384) void k3_fused(
    const float* __restrict__ ai, const float* __restrict__ lf,
    const float* __restrict__ zk, const float* __restrict__ co,
    const float* __restrict__ q, const float* __restrict__ xp,
    float* __restrict__ zp, float* __restrict__ Gc) {
    __shared__ float red[6];
    __shared__ float gbc;
    int tid = threadIdx.x;
    int c = blockIdx.x;
    int ts = c * CH;
    int te = (ts + CH < TP) ? ts + CH : TP;
    float L = co[c * H + tid];
    float qb = q[tid];
    float zacc = 0.0f;
    float gsum = 0.0f;
    int wv = tid >> 6, lane = tid & 63;
    for (int t = te - 1; t >= ts; --t) {
        int idx = t * H + tid;
        float w = __expf(ai[idx] + L) * zk[idx] * qb;
        L += lf[idx];
        float s = w;
        for (int off = 32; off; off >>= 1) s += __shfl_down(s, off, 64);
        if (lane == 0) red[wv] = s;
        __syncthreads();
        if (tid == 0) gbc = ((red[0] + red[1]) + (red[2] + red[3])) + (red[4] + red[5]);
        __syncthreads();
        float g = gbc;
        gsum += g;
        if (tid < 256) zacc = fmaf(g, xp[t * 256 + tid], zacc);
    }
    if (tid < 256) zp[c * 256 + tid] = zacc;
    if (tid == 0) Gc[c] = gsum;
}

// ---------- K6: finalize — sum partials, h[a] = o[a]*(Wv[a]·z + bv[a]*G)/max(|G|,1) ----------
__global__ void k6_out(const float* __restrict__ Gc, const float* __restrict__ zp,
                       const float* __restrict__ Wv, const float* __restrict__ bv,
                       const float* __restrict__ o, float* __restrict__ out) {
    __shared__ float zl[256];
    __shared__ float Gs;
    int tid = threadIdx.x;  // 384 threads
    if (tid < 256) {
        float acc = 0.0f;
        for (int c = 0; c < NC; ++c) acc += zp[c * 256 + tid];
        zl[tid] = acc;
    }
    if (tid == 0) {
        float G = 0.0f;
        for (int c = 0; c < NC; ++c) G += Gc[c];
        Gs = G;
    }
    __syncthreads();
    float G = Gs;
    float acc = bv[tid] * G;
    const float4* wrow = (const float4*)(Wv + tid * 256);
    const float4* zl4 = (const float4*)zl;
    for (int f = 0; f < 64; ++f) {
        float4 wz = wrow[f];
        float4 zv = zl4[f];
        acc = fmaf(wz.x, zv.x, fmaf(wz.y, zv.y, fmaf(wz.z, zv.z, fmaf(wz.w, zv.w, acc))));
    }
    out[tid] = o[tid] * acc / fmaxf(fabsf(G), 1.0f);
}

extern "C" void kernel_launch(void* const* d_in, const int* in_sizes, int n_in,
                              void* d_out, int out_size, void* d_ws, size_t ws_size,
                              hipStream_t stream) {
    const float* x  = (const float*)d_in[0];
    const float* Wq = (const float*)d_in[1];  const float* bq = (const float*)d_in[2];
    const float* Wk = (const float*)d_in[3];  const float* bk = (const float*)d_in[4];
    const float* Wv = (const float*)d_in[5];  const float* bv = (const float*)d_in[6];
    const float* Wi = (const float*)d_in[7];  const float* bi = (const float*)d_in[8];
    const float* Wf = (const float*)d_in[9];  const float* bf = (const float*)d_in[10];
    const float* Wo = (const float*)d_in[11]; const float* bo = (const float*)d_in[12];
    const float* cw = (const float*)d_in[13]; const float* cb = (const float*)d_in[14];
    float* out = (float*)d_out;

    float* ws = (float*)d_ws;
    // workspace layout (floats); ~2.97M floats (~11.9 MB)
    float* xp  = ws;                       // TP*F   = 525056
    float* zk  = xp  + TP * F;             // TP*H   = 787584
    float* ai  = zk  + TP * H;             // TP*H
    float* lf  = ai  + TP * H;             // TP*H
    float* cs  = lf  + TP * H;             // NC*H   = 49536 (scan in place -> co)
    float* qv  = cs  + NC * H;             // H
    float* ov  = qv  + H;                  // H
    float* zp  = ov  + H;                  // NC*F   = 33024
    float* Gc  = zp  + NC * F;             // NC (pad 132)

    k1_conv<<<TP, 256, 0, stream>>>(x, cw, cb, xp);
    k2_proj<<<dim3(NC, 8), 256, 0, stream>>>(xp, Wk, bk, Wi, bi, Wf, bf, zk, ai, lf, cs);
    k2b_qo<<<1, 384, 0, stream>>>(xp, Wq, bq, Wo, bo, qv, ov);
    k3b_scan<<<1, 384, 0, stream>>>(cs);
    k3_fused<<<NC, 384, 0, stream>>>(ai, lf, zk, cs, qv, xp, zp, Gc);
    k6_out<<<1, 384, 0, stream>>>(Gc, zp, Wv, bv, ov, out);
}

// Round 3
// 217.748 us; speedup vs baseline: 1.5622x; 1.2658x over previous
//
#include <hip/hip_runtime.h>
#include <math.h>

#define T_IN 2048
#define TP   2051   // T+3 conv output length
#define F    256
#define H    384
#define CH   16     // chunk = k2's t-tile
#define NC   129    // ceil(TP/16)
#define BK   16     // k2 K-tile
#define SW   132    // LDS W stride (128 b + pad 4): 2-way-conflict-free, 8B-aligned reads

__device__ __forceinline__ float logsig(float z) {
    return (z >= 0.0f) ? -log1pf(__expf(-z)) : z - log1pf(__expf(z));
}

// ---------- K1: conv1d (kernel=4, pad 3/3) -> xp (TP x F), float4 ----------
__global__ void k1_conv(const float* __restrict__ x, const float* __restrict__ cw,
                        const float* __restrict__ cb, float* __restrict__ xp) {
    int t = blockIdx.x;
    int f4 = threadIdx.x;  // 0..63
    float w[4] = {cw[0], cw[1], cw[2], cw[3]};
    float b = cb[0];
    float4 acc = {b, b, b, b};
    int i0 = t - 3;
    const float4* x4 = (const float4*)x;
    #pragma unroll
    for (int j = 0; j < 4; ++j) {
        int tt = i0 + j;
        if (tt >= 0 && tt < T_IN) {
            float4 xv = x4[tt * 64 + f4];
            acc.x = fmaf(w[j], xv.x, acc.x);
            acc.y = fmaf(w[j], xv.y, acc.y);
            acc.z = fmaf(w[j], xv.z, acc.z);
            acc.w = fmaf(w[j], xv.w, acc.w);
        }
    }
    ((float4*)xp)[t * 64 + f4] = acc;
}

// ---------- K2: register-tiled SGEMM: zk/ai/lf projections + chunk lf-sums ----------
// grid (129, 3), 256 threads. Tile: 16 t x 128 b x 3 matrices.
// Threads: tx = tid&31 (b), ty = tid>>5 (t). Per thread: 2 t x 4 b x 3 = 24 acc.
__global__ __launch_bounds__(256) void k2_proj(
    const float* __restrict__ xp,
    const float* __restrict__ Wk, const float* __restrict__ bk,
    const float* __restrict__ Wi, const float* __restrict__ bi,
    const float* __restrict__ Wf, const float* __restrict__ bf,
    float* __restrict__ zk, float* __restrict__ ai, float* __restrict__ lf,
    float* __restrict__ cs) {
    __shared__ float alds[BK][16];       // xp transposed [k][t]
    __shared__ float wlds[3][BK][SW];    // W transposed [j][k][b]
    __shared__ float csred[8][128];      // lf partial sums per ty-group
    int tid = threadIdx.x;
    int t0 = blockIdx.x * 16;
    int b0 = blockIdx.y * 128;
    int tx = tid & 31, ty = tid >> 5;
    const float* Wg[3] = {Wk, Wi, Wf};

    float acc[3][8];
    #pragma unroll
    for (int j = 0; j < 3; ++j)
        #pragma unroll
        for (int u = 0; u < 8; ++u) acc[j][u] = 0.0f;

    int xr = tid >> 4, xk = tid & 15;   // xp staging: row 0..15, k 0..15
    int wr = tid >> 2, wsl = tid & 3;   // W staging: row 0..63, k-slot 0..3

    for (int k0 = 0; k0 < 256; k0 += BK) {
        __syncthreads();
        // xp tile -> alds[k][t]
        float xv = 0.0f;
        int tg = t0 + xr;
        if (tg < TP) xv = xp[tg * 256 + k0 + xk];
        alds[xk][xr] = xv;
        // W tiles -> wlds[j][k][b] (transpose on store; 2-way conflicts only)
        #pragma unroll
        for (int j = 0; j < 3; ++j) {
            const float* wg = Wg[j];
            #pragma unroll
            for (int h = 0; h < 2; ++h) {
                int row = wr + h * 64;
                float4 wv = *(const float4*)&wg[(b0 + row) * 256 + k0 + wsl * 4];
                wlds[j][wsl * 4 + 0][row] = wv.x;
                wlds[j][wsl * 4 + 1][row] = wv.y;
                wlds[j][wsl * 4 + 2][row] = wv.z;
                wlds[j][wsl * 4 + 3][row] = wv.w;
            }
        }
        __syncthreads();
        #pragma unroll
        for (int kk = 0; kk < BK; ++kk) {
            float2 a2 = *(const float2*)&alds[kk][ty * 2];
            #pragma unroll
            for (int j = 0; j < 3; ++j) {
                float2 bA = *(const float2*)&wlds[j][kk][2 * tx];
                float2 bB = *(const float2*)&wlds[j][kk][64 + 2 * tx];
                acc[j][0] = fmaf(a2.x, bA.x, acc[j][0]);
                acc[j][1] = fmaf(a2.x, bA.y, acc[j][1]);
                acc[j][2] = fmaf(a2.x, bB.x, acc[j][2]);
                acc[j][3] = fmaf(a2.x, bB.y, acc[j][3]);
                acc[j][4] = fmaf(a2.y, bA.x, acc[j][4]);
                acc[j][5] = fmaf(a2.y, bA.y, acc[j][5]);
                acc[j][6] = fmaf(a2.y, bB.x, acc[j][6]);
                acc[j][7] = fmaf(a2.y, bB.y, acc[j][7]);
            }
        }
    }
    // epilogue: bias + activations + stores + lf chunk-sum fold
    int bA0 = b0 + 2 * tx, bB0 = b0 + 64 + 2 * tx;
    float2 bkA = *(const float2*)&bk[bA0], bkB = *(const float2*)&bk[bB0];
    float2 biA = *(const float2*)&bi[bA0], biB = *(const float2*)&bi[bB0];
    float2 bfA = *(const float2*)&bf[bA0], bfB = *(const float2*)&bf[bB0];
    const float sc = 0.05103103630798287f;  // 1/sqrt(384)
    float lfs0 = 0, lfs1 = 0, lfs2 = 0, lfs3 = 0;
    #pragma unroll
    for (int tt = 0; tt < 2; ++tt) {
        int t = t0 + ty * 2 + tt;
        if (t < TP) {
            int row = t * H;
            int o = tt * 4;
            float2 v;
            v.x = (acc[0][o + 0] + bkA.x) * sc; v.y = (acc[0][o + 1] + bkA.y) * sc;
            *(float2*)&zk[row + bA0] = v;
            v.x = (acc[0][o + 2] + bkB.x) * sc; v.y = (acc[0][o + 3] + bkB.y) * sc;
            *(float2*)&zk[row + bB0] = v;
            v.x = acc[1][o + 0] + biA.x; v.y = acc[1][o + 1] + biA.y;
            *(float2*)&ai[row + bA0] = v;
            v.x = acc[1][o + 2] + biB.x; v.y = acc[1][o + 3] + biB.y;
            *(float2*)&ai[row + bB0] = v;
            float l0 = logsig(acc[2][o + 0] + bfA.x);
            float l1 = logsig(acc[2][o + 1] + bfA.y);
            float l2 = logsig(acc[2][o + 2] + bfB.x);
            float l3 = logsig(acc[2][o + 3] + bfB.y);
            v.x = l0; v.y = l1; *(float2*)&lf[row + bA0] = v;
            v.x = l2; v.y = l3; *(float2*)&lf[row + bB0] = v;
            lfs0 += l0; lfs1 += l1; lfs2 += l2; lfs3 += l3;
        }
    }
    float2 w2;
    w2.x = lfs0; w2.y = lfs1; *(float2*)&csred[ty][2 * tx] = w2;
    w2.x = lfs2; w2.y = lfs3; *(float2*)&csred[ty][64 + 2 * tx] = w2;
    __syncthreads();
    if (tid < 128) {
        float s = 0.0f;
        #pragma unroll
        for (int y = 0; y < 8; ++y) s += csred[y][tid];
        cs[blockIdx.x * H + b0 + tid] = s;
    }
}

// ---------- K2b: q and o at the final timestep only ----------
__global__ void k2b_qo(const float* __restrict__ xp,
                       const float* __restrict__ Wq, const float* __restrict__ bq,
                       const float* __restrict__ Wo, const float* __restrict__ bo,
                       float* __restrict__ q, float* __restrict__ o) {
    __shared__ float xl[256];
    int tid = threadIdx.x;  // 384 threads
    if (tid < 256) xl[tid] = xp[(TP - 1) * 256 + tid];
    __syncthreads();
    float aq = 0.0f, ao = 0.0f;
    const float4* wq = (const float4*)(Wq + tid * 256);
    const float4* wo = (const float4*)(Wo + tid * 256);
    const float4* xl4 = (const float4*)xl;
    #pragma unroll 8
    for (int f = 0; f < 64; ++f) {
        float4 xv = xl4[f];
        float4 q4 = wq[f], o4 = wo[f];
        aq = fmaf(xv.x, q4.x, fmaf(xv.y, q4.y, fmaf(xv.z, q4.z, fmaf(xv.w, q4.w, aq))));
        ao = fmaf(xv.x, o4.x, fmaf(xv.y, o4.y, fmaf(xv.z, o4.z, fmaf(xv.w, o4.w, ao))));
    }
    q[tid] = aq + bq[tid];
    float zo = ao + bo[tid];
    o[tid] = 1.0f / (1.0f + __expf(-zo));
}

// ---------- K3b: reverse exclusive scan over chunk sums (separate in/out) ----------
__global__ void k3b_scan(const float* __restrict__ cs, float* __restrict__ co) {
    int b = threadIdx.x;  // 384 threads
    float L = 0.0f;
    #pragma unroll 4
    for (int c = NC - 1; c >= 0; --c) {
        co[c * H + b] = L;
        L += cs[c * H + b];
    }
}

// ---------- K3: fused w -> per-wave g partials -> (G, z) chunk partials ----------
// grid NC x 384 threads (6 waves). No barriers inside the t-loop:
// z = sum_w sum_t g^w_t * xp_t, G = sum_w sum_t g^w_t  (per-wave decomposition)
__global__ __launch_bounds__(384) void k3_fused(
    const float* __restrict__ ai, const float* __restrict__ lf,
    const float* __restrict__ zk, const float* __restrict__ co,
    const float* __restrict__ q, const float* __restrict__ xp,
    float* __restrict__ zp, float* __restrict__ Gc) {
    __shared__ float zred[6][256];
    __shared__ float gred[6];
    int tid = threadIdx.x;
    int w = tid >> 6, lane = tid & 63;
    int c = blockIdx.x;
    int ts = c * CH;
    int te = (ts + CH < TP) ? ts + CH : TP;
    float L = co[c * H + tid];
    float qb = q[tid];
    float z0 = 0, z1 = 0, z2 = 0, z3 = 0;
    float gsum = 0.0f;
    #pragma unroll 4
    for (int t = te - 1; t >= ts; --t) {
        int idx = t * H + tid;
        float wv = __expf(ai[idx] + L) * zk[idx] * qb;
        L += lf[idx];
        float s = wv;
        s += __shfl_xor(s, 1, 64);
        s += __shfl_xor(s, 2, 64);
        s += __shfl_xor(s, 4, 64);
        s += __shfl_xor(s, 8, 64);
        s += __shfl_xor(s, 16, 64);
        s += __shfl_xor(s, 32, 64);
        gsum += s;
        float4 xv = *(const float4*)&xp[t * 256 + lane * 4];
        z0 = fmaf(s, xv.x, z0);
        z1 = fmaf(s, xv.y, z1);
        z2 = fmaf(s, xv.z, z2);
        z3 = fmaf(s, xv.w, z3);
    }
    zred[w][lane * 4 + 0] = z0;
    zred[w][lane * 4 + 1] = z1;
    zred[w][lane * 4 + 2] = z2;
    zred[w][lane * 4 + 3] = z3;
    if (lane == 0) gred[w] = gsum;
    __syncthreads();
    if (tid < 256) {
        float s = 0.0f;
        #pragma unroll
        for (int y = 0; y < 6; ++y) s += zred[y][tid];
        zp[c * 256 + tid] = s;
    }
    if (tid == 0) Gc[c] = gred[0] + gred[1] + gred[2] + gred[3] + gred[4] + gred[5];
}

// ---------- K6: finalize ----------
__global__ void k6_out(const float* __restrict__ Gc, const float* __restrict__ zp,
                       const float* __restrict__ Wv, const float* __restrict__ bv,
                       const float* __restrict__ o, float* __restrict__ out) {
    __shared__ float zl[256];
    __shared__ float Gs;
    int tid = threadIdx.x;  // 384 threads
    if (tid < 256) {
        float acc = 0.0f;
        #pragma unroll 4
        for (int c = 0; c < NC; ++c) acc += zp[c * 256 + tid];
        zl[tid] = acc;
    }
    if (tid == 0) {
        float G = 0.0f;
        for (int c = 0; c < NC; ++c) G += Gc[c];
        Gs = G;
    }
    __syncthreads();
    float G = Gs;
    float acc = bv[tid] * G;
    const float4* wrow = (const float4*)(Wv + tid * 256);
    const float4* zl4 = (const float4*)zl;
    #pragma unroll 8
    for (int f = 0; f < 64; ++f) {
        float4 wz = wrow[f];
        float4 zv = zl4[f];
        acc = fmaf(wz.x, zv.x, fmaf(wz.y, zv.y, fmaf(wz.z, zv.z, fmaf(wz.w, zv.w, acc))));
    }
    out[tid] = o[tid] * acc / fmaxf(fabsf(G), 1.0f);
}

extern "C" void kernel_launch(void* const* d_in, const int* in_sizes, int n_in,
                              void* d_out, int out_size, void* d_ws, size_t ws_size,
                              hipStream_t stream) {
    const float* x  = (const float*)d_in[0];
    const float* Wq = (const float*)d_in[1];  const float* bq = (const float*)d_in[2];
    const float* Wk = (const float*)d_in[3];  const float* bk = (const float*)d_in[4];
    const float* Wv = (const float*)d_in[5];  const float* bv = (const float*)d_in[6];
    const float* Wi = (const float*)d_in[7];  const float* bi = (const float*)d_in[8];
    const float* Wf = (const float*)d_in[9];  const float* bf = (const float*)d_in[10];
    const float* Wo = (const float*)d_in[11]; const float* bo = (const float*)d_in[12];
    const float* cw = (const float*)d_in[13]; const float* cb = (const float*)d_in[14];
    float* out = (float*)d_out;

    float* ws = (float*)d_ws;
    float* xp  = ws;                       // TP*F   = 525056
    float* zk  = xp  + TP * F;             // TP*H   = 787584
    float* ai  = zk  + TP * H;             // TP*H
    float* lf  = ai  + TP * H;             // TP*H
    float* cs  = lf  + TP * H;             // NC*H   = 49536
    float* co  = cs  + NC * H;             // NC*H
    float* qv  = co  + NC * H;             // H
    float* ov  = qv  + H;                  // H
    float* zp  = ov  + H;                  // NC*F   = 33024
    float* Gc  = zp  + NC * F;             // NC (pad 132)

    k1_conv<<<TP, 64, 0, stream>>>(x, cw, cb, xp);
    k2_proj<<<dim3(NC, 3), 256, 0, stream>>>(xp, Wk, bk, Wi, bi, Wf, bf, zk, ai, lf, cs);
    k2b_qo<<<1, 384, 0, stream>>>(xp, Wq, bq, Wo, bo, qv, ov);
    k3b_scan<<<1, 384, 0, stream>>>(cs, co);
    k3_fused<<<NC, 384, 0, stream>>>(ai, lf, zk, co, qv, xp, zp, Gc);
    k6_out<<<1, 384, 0, stream>>>(Gc, zp, Wv, bv, ov, out);
}

// Round 4
// 188.375 us; speedup vs baseline: 1.8058x; 1.1559x over previous
//
#include <hip/hip_runtime.h>
#include <math.h>

#define T_IN 2048
#define TP   2051   // T+3 conv output length
#define F    256
#define H    384
#define BK   16     // k2 K-tile
#define NT2  129    // 16-t tiles in k2
#define NCS  258    // scan entries = 8-t chunks = 2*NT2
#define NC3  257    // k3 chunks of 8 covering TP
#define SWA  20     // alds stride (pad 16->20: 2-way max, float2-aligned)
#define SWW  68     // wlds stride (64+4 pad: 2-way max)

__device__ __forceinline__ float logsig(float z) {
    return (z >= 0.0f) ? -log1pf(__expf(-z)) : z - log1pf(__expf(z));
}

// ---------- K1: conv1d (kernel=4, pad 3/3) -> xp (TP x F) ----------
__global__ __launch_bounds__(256) void k1_conv(const float* __restrict__ x,
                        const float* __restrict__ cw,
                        const float* __restrict__ cb, float* __restrict__ xp) {
    int t = blockIdx.x * 4 + (threadIdx.x >> 6);
    int f4 = threadIdx.x & 63;
    if (t >= TP) return;
    float w[4] = {cw[0], cw[1], cw[2], cw[3]};
    float b = cb[0];
    float4 acc = {b, b, b, b};
    int i0 = t - 3;
    const float4* x4 = (const float4*)x;
    #pragma unroll
    for (int j = 0; j < 4; ++j) {
        int tt = i0 + j;
        if (tt >= 0 && tt < T_IN) {
            float4 xv = x4[tt * 64 + f4];
            acc.x = fmaf(w[j], xv.x, acc.x);
            acc.y = fmaf(w[j], xv.y, acc.y);
            acc.z = fmaf(w[j], xv.z, acc.z);
            acc.w = fmaf(w[j], xv.w, acc.w);
        }
    }
    ((float4*)xp)[t * 64 + f4] = acc;
}

// ---------- K2: register-tiled SGEMM, tile 16t x 64b x 3 mats, grid (129,6) ----------
// Threads: tx=tid&31 (2 b's), ty=tid>>5 (2 t's). 12 accumulators/thread.
// Epilogue folds lf chunk-sums at 8-t granularity -> cs[258][H].
__global__ __launch_bounds__(256) void k2_proj(
    const float* __restrict__ xp,
    const float* __restrict__ Wk, const float* __restrict__ bk,
    const float* __restrict__ Wi, const float* __restrict__ bi,
    const float* __restrict__ Wf, const float* __restrict__ bf,
    float* __restrict__ zk, float* __restrict__ ai, float* __restrict__ lf,
    float* __restrict__ cs) {
    __shared__ float alds[BK][SWA];      // xp^T [k][t]
    __shared__ float wlds[3][BK][SWW];   // W^T  [j][k][b]
    __shared__ float csred[8][66];       // lf partials per ty
    int tid = threadIdx.x;
    int t0 = blockIdx.x * 16;
    int b0 = blockIdx.y * 64;
    int tx = tid & 31, ty = tid >> 5;
    const float* Wg[3] = {Wk, Wi, Wf};

    float acc[3][4];
    #pragma unroll
    for (int j = 0; j < 3; ++j)
        #pragma unroll
        for (int u = 0; u < 4; ++u) acc[j][u] = 0.0f;

    int xr = tid >> 4, xk = tid & 15;   // xp staging
    int wr = tid >> 2, wsl = tid & 3;   // W staging

    for (int k0 = 0; k0 < 256; k0 += BK) {
        __syncthreads();
        float xv = 0.0f;
        int tg = t0 + xr;
        if (tg < TP) xv = xp[tg * 256 + k0 + xk];
        alds[xk][xr] = xv;
        #pragma unroll
        for (int j = 0; j < 3; ++j) {
            float4 wv = *(const float4*)&Wg[j][(b0 + wr) * 256 + k0 + wsl * 4];
            wlds[j][wsl * 4 + 0][wr] = wv.x;
            wlds[j][wsl * 4 + 1][wr] = wv.y;
            wlds[j][wsl * 4 + 2][wr] = wv.z;
            wlds[j][wsl * 4 + 3][wr] = wv.w;
        }
        __syncthreads();
        #pragma unroll
        for (int kk = 0; kk < BK; ++kk) {
            float2 a2 = *(const float2*)&alds[kk][ty * 2];
            #pragma unroll
            for (int j = 0; j < 3; ++j) {
                float2 b2 = *(const float2*)&wlds[j][kk][2 * tx];
                acc[j][0] = fmaf(a2.x, b2.x, acc[j][0]);
                acc[j][1] = fmaf(a2.x, b2.y, acc[j][1]);
                acc[j][2] = fmaf(a2.y, b2.x, acc[j][2]);
                acc[j][3] = fmaf(a2.y, b2.y, acc[j][3]);
            }
        }
    }
    // epilogue
    int bA = b0 + 2 * tx;
    float2 bk2 = *(const float2*)&bk[bA];
    float2 bi2 = *(const float2*)&bi[bA];
    float2 bf2 = *(const float2*)&bf[bA];
    const float sc = 0.05103103630798287f;  // 1/sqrt(384)
    float lfs0 = 0.0f, lfs1 = 0.0f;
    #pragma unroll
    for (int tt = 0; tt < 2; ++tt) {
        int t = t0 + ty * 2 + tt;
        if (t < TP) {
            int row = t * H + bA;
            int o = tt * 2;
            float2 v;
            v.x = (acc[0][o] + bk2.x) * sc; v.y = (acc[0][o + 1] + bk2.y) * sc;
            *(float2*)&zk[row] = v;
            v.x = acc[1][o] + bi2.x; v.y = acc[1][o + 1] + bi2.y;
            *(float2*)&ai[row] = v;
            float l0 = logsig(acc[2][o] + bf2.x);
            float l1 = logsig(acc[2][o + 1] + bf2.y);
            v.x = l0; v.y = l1;
            *(float2*)&lf[row] = v;
            lfs0 += l0; lfs1 += l1;
        }
    }
    csred[ty][2 * tx] = lfs0;
    csred[ty][2 * tx + 1] = lfs1;
    __syncthreads();
    // 8-t chunk sums: ty 0..3 -> chunk 2*bx, ty 4..7 -> chunk 2*bx+1
    if (tid < 128) {
        int half = tid >> 6;
        int col = tid & 63;
        float s = csred[half * 4 + 0][col] + csred[half * 4 + 1][col]
                + csred[half * 4 + 2][col] + csred[half * 4 + 3][col];
        cs[(2 * blockIdx.x + half) * H + b0 + col] = s;
    }
}

// ---------- K2b: q/o at final timestep, wave-per-row, grid 96 ----------
__global__ __launch_bounds__(256) void k2b_qo(const float* __restrict__ xp,
        const float* __restrict__ Wq, const float* __restrict__ bq,
        const float* __restrict__ Wo, const float* __restrict__ bo,
        float* __restrict__ q, float* __restrict__ o) {
    int tid = threadIdx.x;
    int lane = tid & 63;
    int row = blockIdx.x * 4 + (tid >> 6);
    float4 xv = *(const float4*)&xp[(TP - 1) * 256 + lane * 4];
    float4 q4 = *(const float4*)&Wq[row * 256 + lane * 4];
    float4 o4 = *(const float4*)&Wo[row * 256 + lane * 4];
    float aq = fmaf(xv.x, q4.x, fmaf(xv.y, q4.y, fmaf(xv.z, q4.z, xv.w * q4.w)));
    float ao = fmaf(xv.x, o4.x, fmaf(xv.y, o4.y, fmaf(xv.z, o4.z, xv.w * o4.w)));
    #pragma unroll
    for (int off = 32; off; off >>= 1) {
        aq += __shfl_down(aq, off, 64);
        ao += __shfl_down(ao, off, 64);
    }
    if (lane == 0) {
        q[row] = aq + bq[row];
        o[row] = 1.0f / (1.0f + __expf(-(ao + bo[row])));
    }
}

// ---------- K3b: reverse exclusive scan over 258 chunk sums, grid 6x64 ----------
__global__ __launch_bounds__(64) void k3b_scan(const float* __restrict__ cs,
                                               float* __restrict__ co) {
    int b = blockIdx.x * 64 + threadIdx.x;
    float L = 0.0f;
    #pragma unroll 8
    for (int c = NCS - 1; c >= 0; --c) {
        co[c * H + b] = L;
        L += cs[c * H + b];
    }
}

// ---------- K3: fused w -> per-wave g partials -> (G, z) chunk partials ----------
// grid NC3 x 384 (6 waves), chunk = 8 t. No barriers in the t-loop.
__global__ __launch_bounds__(384) void k3_fused(
    const float* __restrict__ ai, const float* __restrict__ lf,
    const float* __restrict__ zk, const float* __restrict__ co,
    const float* __restrict__ q, const float* __restrict__ xp,
    float* __restrict__ zp, float* __restrict__ Gc) {
    __shared__ float zred[6][256];
    __shared__ float gred[6];
    int tid = threadIdx.x;
    int w = tid >> 6, lane = tid & 63;
    int c = blockIdx.x;
    int ts = c * 8;
    int te = (ts + 8 < TP) ? ts + 8 : TP;
    float L = co[c * H + tid];
    float qb = q[tid];
    float z0 = 0, z1 = 0, z2 = 0, z3 = 0;
    float gsum = 0.0f;
    #pragma unroll 8
    for (int t = te - 1; t >= ts; --t) {
        int idx = t * H + tid;
        float wv = __expf(ai[idx] + L) * zk[idx] * qb;
        L += lf[idx];
        float s = wv;
        s += __shfl_xor(s, 1, 64);
        s += __shfl_xor(s, 2, 64);
        s += __shfl_xor(s, 4, 64);
        s += __shfl_xor(s, 8, 64);
        s += __shfl_xor(s, 16, 64);
        s += __shfl_xor(s, 32, 64);
        gsum += s;
        float4 xv = *(const float4*)&xp[t * 256 + lane * 4];
        z0 = fmaf(s, xv.x, z0);
        z1 = fmaf(s, xv.y, z1);
        z2 = fmaf(s, xv.z, z2);
        z3 = fmaf(s, xv.w, z3);
    }
    zred[w][lane * 4 + 0] = z0;
    zred[w][lane * 4 + 1] = z1;
    zred[w][lane * 4 + 2] = z2;
    zred[w][lane * 4 + 3] = z3;
    if (lane == 0) gred[w] = gsum;
    __syncthreads();
    if (tid < 256) {
        float s = 0.0f;
        #pragma unroll
        for (int y = 0; y < 6; ++y) s += zred[y][tid];
        zp[c * 256 + tid] = s;
    }
    if (tid == 0)
        Gc[c] = gred[0] + gred[1] + gred[2] + gred[3] + gred[4] + gred[5];
}

// ---------- K5r: reduce zp -> z[256], Gc -> G ----------
__global__ __launch_bounds__(256) void k5r(const float* __restrict__ zp,
        const float* __restrict__ Gc, float* __restrict__ z, float* __restrict__ G) {
    int tid = threadIdx.x;
    float acc = 0.0f;
    #pragma unroll 8
    for (int c = 0; c < NC3; ++c) acc += zp[c * 256 + tid];
    z[tid] = acc;
    if (tid < 64) {
        float g = 0.0f;
        for (int c = tid; c < NC3; c += 64) g += Gc[c];
        #pragma unroll
        for (int off = 32; off; off >>= 1) g += __shfl_down(g, off, 64);
        if (tid == 0) G[0] = g;
    }
}

// ---------- K6: wave-per-row GEMV finalize, grid 96 ----------
__global__ __launch_bounds__(256) void k6_out(const float* __restrict__ z,
        const float* __restrict__ G,
        const float* __restrict__ Wv, const float* __restrict__ bv,
        const float* __restrict__ o, float* __restrict__ out) {
    int tid = threadIdx.x;
    int lane = tid & 63;
    int row = blockIdx.x * 4 + (tid >> 6);
    float Gv = G[0];
    float4 zv = *(const float4*)&z[lane * 4];
    float4 wv = *(const float4*)&Wv[row * 256 + lane * 4];
    float acc = fmaf(zv.x, wv.x, fmaf(zv.y, wv.y, fmaf(zv.z, wv.z, zv.w * wv.w)));
    #pragma unroll
    for (int off = 32; off; off >>= 1) acc += __shfl_down(acc, off, 64);
    if (lane == 0)
        out[row] = o[row] * (acc + bv[row] * Gv) / fmaxf(fabsf(Gv), 1.0f);
}

extern "C" void kernel_launch(void* const* d_in, const int* in_sizes, int n_in,
                              void* d_out, int out_size, void* d_ws, size_t ws_size,
                              hipStream_t stream) {
    const float* x  = (const float*)d_in[0];
    const float* Wq = (const float*)d_in[1];  const float* bq = (const float*)d_in[2];
    const float* Wk = (const float*)d_in[3];  const float* bk = (const float*)d_in[4];
    const float* Wv = (const float*)d_in[5];  const float* bv = (const float*)d_in[6];
    const float* Wi = (const float*)d_in[7];  const float* bi = (const float*)d_in[8];
    const float* Wf = (const float*)d_in[9];  const float* bf = (const float*)d_in[10];
    const float* Wo = (const float*)d_in[11]; const float* bo = (const float*)d_in[12];
    const float* cw = (const float*)d_in[13]; const float* cb = (const float*)d_in[14];
    float* out = (float*)d_out;

    float* ws = (float*)d_ws;
    float* xp  = ws;                       // TP*F   = 525056
    float* zk  = xp  + TP * F;             // TP*H   = 787584
    float* ai  = zk  + TP * H;             // TP*H
    float* lf  = ai  + TP * H;             // TP*H
    float* cs  = lf  + TP * H;             // NCS*H  = 99072
    float* co  = cs  + NCS * H;            // NCS*H
    float* qv  = co  + NCS * H;            // H
    float* ov  = qv  + H;                  // H
    float* zp  = ov  + H;                  // NC3*F  = 65792
    float* Gc  = zp  + NC3 * F;            // NC3 (pad 260)
    float* zf  = Gc  + 260;                // F
    float* Gf  = zf  + F;                  // 1

    k1_conv<<<(TP + 3) / 4, 256, 0, stream>>>(x, cw, cb, xp);
    k2_proj<<<dim3(NT2, 6), 256, 0, stream>>>(xp, Wk, bk, Wi, bi, Wf, bf, zk, ai, lf, cs);
    k2b_qo<<<96, 256, 0, stream>>>(xp, Wq, bq, Wo, bo, qv, ov);
    k3b_scan<<<6, 64, 0, stream>>>(cs, co);
    k3_fused<<<NC3, 384, 0, stream>>>(ai, lf, zk, co, qv, xp, zp, Gc);
    k5r<<<1, 256, 0, stream>>>(zp, Gc, zf, Gf);
    k6_out<<<96, 256, 0, stream>>>(zf, Gf, Wv, bv, ov, out);
}

// Round 5
// 174.080 us; speedup vs baseline: 1.9541x; 1.0821x over previous
//
#include <hip/hip_runtime.h>
#include <math.h>

#define T_IN 2048
#define TP   2051   // T+3 conv output length
#define F    256
#define H    384
#define BK   16     // k2 K-tile
#define NT2  129    // 16-t tiles in k2
#define NCS  258    // 8-t chunks = 2*NT2
#define NC3  257    // k3 chunks of 8 covering TP

__device__ __forceinline__ float logsig(float z) {
    return (z >= 0.0f) ? -log1pf(__expf(-z)) : z - log1pf(__expf(z));
}

// ---------- K1: conv1d (kernel=4, pad 3/3) -> xp (TP x F) ----------
__global__ __launch_bounds__(256) void k1_conv(const float* __restrict__ x,
                        const float* __restrict__ cw,
                        const float* __restrict__ cb, float* __restrict__ xp) {
    int t = blockIdx.x * 4 + (threadIdx.x >> 6);
    int f4 = threadIdx.x & 63;
    if (t >= TP) return;
    float w[4] = {cw[0], cw[1], cw[2], cw[3]};
    float b = cb[0];
    float4 acc = {b, b, b, b};
    int i0 = t - 3;
    const float4* x4 = (const float4*)x;
    #pragma unroll
    for (int j = 0; j < 4; ++j) {
        int tt = i0 + j;
        if (tt >= 0 && tt < T_IN) {
            float4 xv = x4[tt * 64 + f4];
            acc.x = fmaf(w[j], xv.x, acc.x);
            acc.y = fmaf(w[j], xv.y, acc.y);
            acc.z = fmaf(w[j], xv.z, acc.z);
            acc.w = fmaf(w[j], xv.w, acc.w);
        }
    }
    ((float4*)xp)[t * 64 + f4] = acc;
}

// ---------- K2: m4xn4 register-tiled SGEMM, tile 16t x 64b x 3 mats ----------
// grid (129,6), 64 threads (1 wave). tx=tid&15 -> 4 b's, ty=tid>>4 -> 4 t's.
// 48 accs/thread: F=48 FMA per 16 LDS words -> VALU-bound (F>=4W with
// broadcast-merged float4 b-reads). Epilogue folds 8-t lf chunk sums -> cs.
__global__ __launch_bounds__(64) void k2_proj(
    const float* __restrict__ xp,
    const float* __restrict__ Wk, const float* __restrict__ bk,
    const float* __restrict__ Wi, const float* __restrict__ bi,
    const float* __restrict__ Wf, const float* __restrict__ bf,
    float* __restrict__ zk, float* __restrict__ ai, float* __restrict__ lf,
    float* __restrict__ cs) {
    __shared__ float alds[BK][20];      // xp^T [k][t], pad 16->20 (2-way max)
    __shared__ float wlds[3][BK][68];   // W^T  [j][k][b], pad 64->68
    __shared__ float csred[4][68];
    int tid = threadIdx.x;
    int t0 = blockIdx.x * 16, b0 = blockIdx.y * 64;
    int tx = tid & 15, ty = tid >> 4;
    const float* Wg[3] = {Wk, Wi, Wf};
    float acc[3][16];
    #pragma unroll
    for (int j = 0; j < 3; ++j)
        #pragma unroll
        for (int u = 0; u < 16; ++u) acc[j][u] = 0.0f;

    int at = tid >> 2;          // staging t-row / b-row-mod-16
    int ak = (tid & 3) * 4;     // staging k quad

    for (int k0 = 0; k0 < 256; k0 += BK) {
        __syncthreads();
        float4 xv = {0.f, 0.f, 0.f, 0.f};
        if (t0 + at < TP) xv = *(const float4*)&xp[(t0 + at) * 256 + k0 + ak];
        alds[ak + 0][at] = xv.x; alds[ak + 1][at] = xv.y;
        alds[ak + 2][at] = xv.z; alds[ak + 3][at] = xv.w;
        #pragma unroll
        for (int j = 0; j < 3; ++j) {
            #pragma unroll
            for (int h = 0; h < 4; ++h) {
                int row = h * 16 + at;
                float4 wv = *(const float4*)&Wg[j][(b0 + row) * 256 + k0 + ak];
                wlds[j][ak + 0][row] = wv.x; wlds[j][ak + 1][row] = wv.y;
                wlds[j][ak + 2][row] = wv.z; wlds[j][ak + 3][row] = wv.w;
            }
        }
        __syncthreads();
        #pragma unroll
        for (int kk = 0; kk < BK; ++kk) {
            float4 a4 = *(const float4*)&alds[kk][ty * 4];
            #pragma unroll
            for (int j = 0; j < 3; ++j) {
                float4 b4 = *(const float4*)&wlds[j][kk][tx * 4];
                acc[j][0]  = fmaf(a4.x, b4.x, acc[j][0]);
                acc[j][1]  = fmaf(a4.x, b4.y, acc[j][1]);
                acc[j][2]  = fmaf(a4.x, b4.z, acc[j][2]);
                acc[j][3]  = fmaf(a4.x, b4.w, acc[j][3]);
                acc[j][4]  = fmaf(a4.y, b4.x, acc[j][4]);
                acc[j][5]  = fmaf(a4.y, b4.y, acc[j][5]);
                acc[j][6]  = fmaf(a4.y, b4.z, acc[j][6]);
                acc[j][7]  = fmaf(a4.y, b4.w, acc[j][7]);
                acc[j][8]  = fmaf(a4.z, b4.x, acc[j][8]);
                acc[j][9]  = fmaf(a4.z, b4.y, acc[j][9]);
                acc[j][10] = fmaf(a4.z, b4.z, acc[j][10]);
                acc[j][11] = fmaf(a4.z, b4.w, acc[j][11]);
                acc[j][12] = fmaf(a4.w, b4.x, acc[j][12]);
                acc[j][13] = fmaf(a4.w, b4.y, acc[j][13]);
                acc[j][14] = fmaf(a4.w, b4.z, acc[j][14]);
                acc[j][15] = fmaf(a4.w, b4.w, acc[j][15]);
            }
        }
    }
    // epilogue
    int bA = b0 + tx * 4;
    float4 bk4 = *(const float4*)&bk[bA];
    float4 bi4 = *(const float4*)&bi[bA];
    float4 bf4 = *(const float4*)&bf[bA];
    const float sc = 0.05103103630798287f;  // 1/sqrt(384)
    float4 lfs = {0.f, 0.f, 0.f, 0.f};
    #pragma unroll
    for (int tt = 0; tt < 4; ++tt) {
        int t = t0 + ty * 4 + tt;
        if (t < TP) {
            int row = t * H + bA;
            int o = tt * 4;
            float4 v;
            v.x = (acc[0][o+0] + bk4.x) * sc; v.y = (acc[0][o+1] + bk4.y) * sc;
            v.z = (acc[0][o+2] + bk4.z) * sc; v.w = (acc[0][o+3] + bk4.w) * sc;
            *(float4*)&zk[row] = v;
            v.x = acc[1][o+0] + bi4.x; v.y = acc[1][o+1] + bi4.y;
            v.z = acc[1][o+2] + bi4.z; v.w = acc[1][o+3] + bi4.w;
            *(float4*)&ai[row] = v;
            float4 l;
            l.x = logsig(acc[2][o+0] + bf4.x); l.y = logsig(acc[2][o+1] + bf4.y);
            l.z = logsig(acc[2][o+2] + bf4.z); l.w = logsig(acc[2][o+3] + bf4.w);
            *(float4*)&lf[row] = l;
            lfs.x += l.x; lfs.y += l.y; lfs.z += l.z; lfs.w += l.w;
        }
    }
    *(float4*)&csred[ty][tx * 4] = lfs;
    __syncthreads();
    {   // ty 0,1 -> chunk 2*bx (t0..t0+7); ty 2,3 -> chunk 2*bx+1
        float s0 = csred[0][tid] + csred[1][tid];
        float s1 = csred[2][tid] + csred[3][tid];
        cs[(2 * blockIdx.x + 0) * H + b0 + tid] = s0;
        cs[(2 * blockIdx.x + 1) * H + b0 + tid] = s1;
    }
}

// ---------- K2b: q/o at final timestep, wave-per-row, grid 96 ----------
__global__ __launch_bounds__(256) void k2b_qo(const float* __restrict__ xp,
        const float* __restrict__ Wq, const float* __restrict__ bq,
        const float* __restrict__ Wo, const float* __restrict__ bo,
        float* __restrict__ q, float* __restrict__ o) {
    int tid = threadIdx.x;
    int lane = tid & 63;
    int row = blockIdx.x * 4 + (tid >> 6);
    float4 xv = *(const float4*)&xp[(TP - 1) * 256 + lane * 4];
    float4 q4 = *(const float4*)&Wq[row * 256 + lane * 4];
    float4 o4 = *(const float4*)&Wo[row * 256 + lane * 4];
    float aq = fmaf(xv.x, q4.x, fmaf(xv.y, q4.y, fmaf(xv.z, q4.z, xv.w * q4.w)));
    float ao = fmaf(xv.x, o4.x, fmaf(xv.y, o4.y, fmaf(xv.z, o4.z, xv.w * o4.w)));
    #pragma unroll
    for (int off = 32; off; off >>= 1) {
        aq += __shfl_down(aq, off, 64);
        ao += __shfl_down(ao, off, 64);
    }
    if (lane == 0) {
        q[row] = aq + bq[row];
        o[row] = 1.0f / (1.0f + __expf(-(ao + bo[row])));
    }
}

// ---------- K3b: reverse exclusive scan over 258 chunk sums, grid 6x64 ----------
__global__ __launch_bounds__(64) void k3b_scan(const float* __restrict__ cs,
                                               float* __restrict__ co) {
    int b = blockIdx.x * 64 + threadIdx.x;
    float L = 0.0f;
    #pragma unroll 16
    for (int c = NCS - 1; c >= 0; --c) {
        co[c * H + b] = L;
        L += cs[c * H + b];
    }
}

// ---------- K3: fused w -> g -> atomic (z, G). grid NC3 x 384, chunk 8 t ----------
// All loads prefetched to registers; L via register suffix-sum (no serial dep).
__global__ __launch_bounds__(384) void k3_fused(
    const float* __restrict__ ai, const float* __restrict__ lf,
    const float* __restrict__ zk, const float* __restrict__ co,
    const float* __restrict__ q, const float* __restrict__ xp,
    float* __restrict__ zf, float* __restrict__ Gf) {
    __shared__ float zred[6][256];
    __shared__ float gred[6];
    int tid = threadIdx.x;
    int w = tid >> 6, lane = tid & 63;
    int c = blockIdx.x, ts = c * 8;
    float co0 = co[c * H + tid];
    float qb = q[tid];
    float aiv[8], lfv[8], zkv[8];
    float4 xv[8];
    if (ts + 8 <= TP) {
        #pragma unroll
        for (int u = 0; u < 8; ++u) {
            int idx = (ts + u) * H + tid;
            aiv[u] = ai[idx]; lfv[u] = lf[idx]; zkv[u] = zk[idx];
            xv[u] = *(const float4*)&xp[(ts + u) * 256 + lane * 4];
        }
    } else {
        #pragma unroll
        for (int u = 0; u < 8; ++u) {
            if (ts + u < TP) {
                int idx = (ts + u) * H + tid;
                aiv[u] = ai[idx]; lfv[u] = lf[idx]; zkv[u] = zk[idx];
                xv[u] = *(const float4*)&xp[(ts + u) * 256 + lane * 4];
            } else {
                aiv[u] = -1e30f; lfv[u] = 0.f; zkv[u] = 0.f;
                xv[u].x = xv[u].y = xv[u].z = xv[u].w = 0.f;
            }
        }
    }
    float S = 0.f, gsum = 0.f;
    float z0 = 0.f, z1 = 0.f, z2 = 0.f, z3 = 0.f;
    #pragma unroll
    for (int u = 7; u >= 0; --u) {
        float wv = __expf(aiv[u] + co0 + S) * zkv[u] * qb;
        S += lfv[u];
        float s = wv;
        s += __shfl_xor(s, 1, 64);
        s += __shfl_xor(s, 2, 64);
        s += __shfl_xor(s, 4, 64);
        s += __shfl_xor(s, 8, 64);
        s += __shfl_xor(s, 16, 64);
        s += __shfl_xor(s, 32, 64);
        gsum += s;
        z0 = fmaf(s, xv[u].x, z0);
        z1 = fmaf(s, xv[u].y, z1);
        z2 = fmaf(s, xv[u].z, z2);
        z3 = fmaf(s, xv[u].w, z3);
    }
    zred[w][lane * 4 + 0] = z0;
    zred[w][lane * 4 + 1] = z1;
    zred[w][lane * 4 + 2] = z2;
    zred[w][lane * 4 + 3] = z3;
    if (lane == 0) gred[w] = gsum;
    __syncthreads();
    if (tid < 256) {
        float s = zred[0][tid] + zred[1][tid] + zred[2][tid]
                + zred[3][tid] + zred[4][tid] + zred[5][tid];
        atomicAdd(&zf[tid], s);
    }
    if (tid == 0)
        atomicAdd(Gf, gred[0] + gred[1] + gred[2] + gred[3] + gred[4] + gred[5]);
}

// ---------- K6: wave-per-row GEMV finalize, grid 96 ----------
__global__ __launch_bounds__(256) void k6_out(const float* __restrict__ zf,
        const float* __restrict__ Gf,
        const float* __restrict__ Wv, const float* __restrict__ bv,
        const float* __restrict__ o, float* __restrict__ out) {
    int tid = threadIdx.x;
    int lane = tid & 63;
    int row = blockIdx.x * 4 + (tid >> 6);
    float Gv = Gf[0];
    float4 zv = *(const float4*)&zf[lane * 4];
    float4 wv = *(const float4*)&Wv[row * 256 + lane * 4];
    float acc = fmaf(zv.x, wv.x, fmaf(zv.y, wv.y, fmaf(zv.z, wv.z, zv.w * wv.w)));
    #pragma unroll
    for (int off = 32; off; off >>= 1) acc += __shfl_down(acc, off, 64);
    if (lane == 0)
        out[row] = o[row] * (acc + bv[row] * Gv) / fmaxf(fabsf(Gv), 1.0f);
}

extern "C" void kernel_launch(void* const* d_in, const int* in_sizes, int n_in,
                              void* d_out, int out_size, void* d_ws, size_t ws_size,
                              hipStream_t stream) {
    const float* x  = (const float*)d_in[0];
    const float* Wq = (const float*)d_in[1];  const float* bq = (const float*)d_in[2];
    const float* Wk = (const float*)d_in[3];  const float* bk = (const float*)d_in[4];
    const float* Wv = (const float*)d_in[5];  const float* bv = (const float*)d_in[6];
    const float* Wi = (const float*)d_in[7];  const float* bi = (const float*)d_in[8];
    const float* Wf = (const float*)d_in[9];  const float* bf = (const float*)d_in[10];
    const float* Wo = (const float*)d_in[11]; const float* bo = (const float*)d_in[12];
    const float* cw = (const float*)d_in[13]; const float* cb = (const float*)d_in[14];
    float* out = (float*)d_out;

    float* ws = (float*)d_ws;
    float* xp  = ws;                       // TP*F   = 525056
    float* zk  = xp  + TP * F;             // TP*H   = 787584
    float* ai  = zk  + TP * H;             // TP*H
    float* lf  = ai  + TP * H;             // TP*H
    float* cs  = lf  + TP * H;             // NCS*H  = 99072
    float* co  = cs  + NCS * H;            // NCS*H
    float* qv  = co  + NCS * H;            // H
    float* ov  = qv  + H;                  // H
    float* zf  = ov  + H;                  // F (z accumulator)
    float* Gf  = zf  + F;                  // 1 (+pad)

    hipMemsetAsync((void*)zf, 0, (F + 4) * sizeof(float), stream);
    k1_conv<<<(TP + 3) / 4, 256, 0, stream>>>(x, cw, cb, xp);
    k2_proj<<<dim3(NT2, 6), 64, 0, stream>>>(xp, Wk, bk, Wi, bi, Wf, bf, zk, ai, lf, cs);
    k2b_qo<<<96, 256, 0, stream>>>(xp, Wq, bq, Wo, bo, qv, ov);
    k3b_scan<<<6, 64, 0, stream>>>(cs, co);
    k3_fused<<<NC3, 384, 0, stream>>>(ai, lf, zk, co, qv, xp, zf, Gf);
    k6_out<<<96, 256, 0, stream>>>(zf, Gf, Wv, bv, ov, out);
}

// Round 6
// 174.055 us; speedup vs baseline: 1.9544x; 1.0001x over previous
//
#include <hip/hip_runtime.h>
#include <math.h>

#define T_IN 2048
#define TP   2051   // T+3 conv output length
#define F    256
#define H    384
#define BK   16     // k2 K-tile
#define NT2  257    // 8-t tiles in k2
#define NCS  257    // 8-t chunks (scan length)
#define NC3  257    // k3 chunks of 8

__device__ __forceinline__ float logsig(float z) {
    return (z >= 0.0f) ? -log1pf(__expf(-z)) : z - log1pf(__expf(z));
}

// ---------- K1: conv1d (kernel=4, pad 3/3) -> xp (TP x F) ----------
__global__ __launch_bounds__(256) void k1_conv(const float* __restrict__ x,
                        const float* __restrict__ cw,
                        const float* __restrict__ cb, float* __restrict__ xp) {
    int t = blockIdx.x * 4 + (threadIdx.x >> 6);
    int f4 = threadIdx.x & 63;
    if (t >= TP) return;
    float w[4] = {cw[0], cw[1], cw[2], cw[3]};
    float b = cb[0];
    float4 acc = {b, b, b, b};
    int i0 = t - 3;
    const float4* x4 = (const float4*)x;
    #pragma unroll
    for (int j = 0; j < 4; ++j) {
        int tt = i0 + j;
        if (tt >= 0 && tt < T_IN) {
            float4 xv = x4[tt * 64 + f4];
            acc.x = fmaf(w[j], xv.x, acc.x);
            acc.y = fmaf(w[j], xv.y, acc.y);
            acc.z = fmaf(w[j], xv.z, acc.z);
            acc.w = fmaf(w[j], xv.w, acc.w);
        }
    }
    ((float4*)xp)[t * 64 + f4] = acc;
}

// ---------- K2: 8t x 64b x 3mats, 256 thr, double-buffered LDS + reg prefetch ----------
// grid (257, 6) = 1542 blocks (~6/CU). tx=tid&31 -> 2 b's, ty=tid>>5 -> 1 t.
// One barrier per K-tile; next-tile global loads overlap current compute.
__global__ __launch_bounds__(256) void k2_proj(
    const float* __restrict__ xp,
    const float* __restrict__ Wk, const float* __restrict__ bk,
    const float* __restrict__ Wi, const float* __restrict__ bi,
    const float* __restrict__ Wf, const float* __restrict__ bf,
    float* __restrict__ zk, float* __restrict__ ai, float* __restrict__ lf,
    float* __restrict__ cs) {
    __shared__ float alds[2][BK][12];     // xp^T [k][t]
    __shared__ float wlds[2][3][BK][66];  // W^T  [j][k][b]
    __shared__ float csred[8][66];
    int tid = threadIdx.x;
    int t0 = blockIdx.x * 8, b0 = blockIdx.y * 64;
    int tx = tid & 31, ty = tid >> 5;
    float2 acc0 = {0.f, 0.f}, acc1 = {0.f, 0.f}, acc2 = {0.f, 0.f};

    int wrow = tid >> 2;          // 0..63 (W row within tile)
    int wk4 = (tid & 3) * 4;      // k quad
    int grow = (b0 + wrow) * 256 + wk4;
    int arow = (t0 + (tid >> 2)) * 256 + wk4;   // valid only for tid<32
    bool aval = (tid < 32) && (t0 + (tid >> 2) < TP);

    float4 aw = {0.f, 0.f, 0.f, 0.f}, ww0, ww1, ww2;
    // prologue: load tile 0
    if (aval) aw = *(const float4*)&xp[arow];
    ww0 = *(const float4*)&Wk[grow];
    ww1 = *(const float4*)&Wi[grow];
    ww2 = *(const float4*)&Wf[grow];

    for (int i = 0; i < 16; ++i) {
        int buf = i & 1;
        if (tid < 32) {
            int tq = tid >> 2;
            alds[buf][wk4 + 0][tq] = aw.x;
            alds[buf][wk4 + 1][tq] = aw.y;
            alds[buf][wk4 + 2][tq] = aw.z;
            alds[buf][wk4 + 3][tq] = aw.w;
        }
        wlds[buf][0][wk4 + 0][wrow] = ww0.x;
        wlds[buf][0][wk4 + 1][wrow] = ww0.y;
        wlds[buf][0][wk4 + 2][wrow] = ww0.z;
        wlds[buf][0][wk4 + 3][wrow] = ww0.w;
        wlds[buf][1][wk4 + 0][wrow] = ww1.x;
        wlds[buf][1][wk4 + 1][wrow] = ww1.y;
        wlds[buf][1][wk4 + 2][wrow] = ww1.z;
        wlds[buf][1][wk4 + 3][wrow] = ww1.w;
        wlds[buf][2][wk4 + 0][wrow] = ww2.x;
        wlds[buf][2][wk4 + 1][wrow] = ww2.y;
        wlds[buf][2][wk4 + 2][wrow] = ww2.z;
        wlds[buf][2][wk4 + 3][wrow] = ww2.w;
        __syncthreads();
        if (i < 15) {
            int k0 = (i + 1) * BK;
            if (aval) aw = *(const float4*)&xp[arow + k0];
            ww0 = *(const float4*)&Wk[grow + k0];
            ww1 = *(const float4*)&Wi[grow + k0];
            ww2 = *(const float4*)&Wf[grow + k0];
        }
        #pragma unroll
        for (int kk = 0; kk < BK; ++kk) {
            float a = alds[buf][kk][ty];
            float2 b0v = *(const float2*)&wlds[buf][0][kk][2 * tx];
            float2 b1v = *(const float2*)&wlds[buf][1][kk][2 * tx];
            float2 b2v = *(const float2*)&wlds[buf][2][kk][2 * tx];
            acc0.x = fmaf(a, b0v.x, acc0.x); acc0.y = fmaf(a, b0v.y, acc0.y);
            acc1.x = fmaf(a, b1v.x, acc1.x); acc1.y = fmaf(a, b1v.y, acc1.y);
            acc2.x = fmaf(a, b2v.x, acc2.x); acc2.y = fmaf(a, b2v.y, acc2.y);
        }
    }
    // epilogue
    int bA = b0 + 2 * tx;
    int t = t0 + ty;
    float2 l2 = {0.f, 0.f};
    if (t < TP) {
        float2 bk2 = *(const float2*)&bk[bA];
        float2 bi2 = *(const float2*)&bi[bA];
        float2 bf2 = *(const float2*)&bf[bA];
        const float sc = 0.05103103630798287f;  // 1/sqrt(384)
        int row = t * H + bA;
        float2 v;
        v.x = (acc0.x + bk2.x) * sc; v.y = (acc0.y + bk2.y) * sc;
        *(float2*)&zk[row] = v;
        v.x = acc1.x + bi2.x; v.y = acc1.y + bi2.y;
        *(float2*)&ai[row] = v;
        l2.x = logsig(acc2.x + bf2.x); l2.y = logsig(acc2.y + bf2.y);
        *(float2*)&lf[row] = l2;
    }
    *(float2*)&csred[ty][2 * tx] = l2;
    __syncthreads();
    if (tid < 64) {
        float s = 0.f;
        #pragma unroll
        for (int y = 0; y < 8; ++y) s += csred[y][tid];
        cs[blockIdx.x * H + b0 + tid] = s;
    }
}

// ---------- K2b: q/o at final timestep, wave-per-row, grid 96 ----------
__global__ __launch_bounds__(256) void k2b_qo(const float* __restrict__ xp,
        const float* __restrict__ Wq, const float* __restrict__ bq,
        const float* __restrict__ Wo, const float* __restrict__ bo,
        float* __restrict__ q, float* __restrict__ o) {
    int tid = threadIdx.x;
    int lane = tid & 63;
    int row = blockIdx.x * 4 + (tid >> 6);
    float4 xv = *(const float4*)&xp[(TP - 1) * 256 + lane * 4];
    float4 q4 = *(const float4*)&Wq[row * 256 + lane * 4];
    float4 o4 = *(const float4*)&Wo[row * 256 + lane * 4];
    float aq = fmaf(xv.x, q4.x, fmaf(xv.y, q4.y, fmaf(xv.z, q4.z, xv.w * q4.w)));
    float ao = fmaf(xv.x, o4.x, fmaf(xv.y, o4.y, fmaf(xv.z, o4.z, xv.w * o4.w)));
    #pragma unroll
    for (int off = 32; off; off >>= 1) {
        aq += __shfl_down(aq, off, 64);
        ao += __shfl_down(ao, off, 64);
    }
    if (lane == 0) {
        q[row] = aq + bq[row];
        o[row] = 1.0f / (1.0f + __expf(-(ao + bo[row])));
    }
}

// ---------- K3b: reverse exclusive scan over 257 chunk sums, grid 6x64 ----------
__global__ __launch_bounds__(64) void k3b_scan(const float* __restrict__ cs,
                                               float* __restrict__ co) {
    int b = blockIdx.x * 64 + threadIdx.x;
    float L = 0.0f;
    #pragma unroll 16
    for (int c = NCS - 1; c >= 0; --c) {
        co[c * H + b] = L;
        L += cs[c * H + b];
    }
}

// ---------- K3: fused w -> g -> atomic (z, G). grid NC3 x 384, chunk 8 t ----------
__global__ __launch_bounds__(384) void k3_fused(
    const float* __restrict__ ai, const float* __restrict__ lf,
    const float* __restrict__ zk, const float* __restrict__ co,
    const float* __restrict__ q, const float* __restrict__ xp,
    float* __restrict__ zf, float* __restrict__ Gf) {
    __shared__ float zred[6][256];
    __shared__ float gred[6];
    int tid = threadIdx.x;
    int w = tid >> 6, lane = tid & 63;
    int c = blockIdx.x, ts = c * 8;
    float co0 = co[c * H + tid];
    float qb = q[tid];
    float aiv[8], lfv[8], zkv[8];
    float4 xv[8];
    if (ts + 8 <= TP) {
        #pragma unroll
        for (int u = 0; u < 8; ++u) {
            int idx = (ts + u) * H + tid;
            aiv[u] = ai[idx]; lfv[u] = lf[idx]; zkv[u] = zk[idx];
            xv[u] = *(const float4*)&xp[(ts + u) * 256 + lane * 4];
        }
    } else {
        #pragma unroll
        for (int u = 0; u < 8; ++u) {
            if (ts + u < TP) {
                int idx = (ts + u) * H + tid;
                aiv[u] = ai[idx]; lfv[u] = lf[idx]; zkv[u] = zk[idx];
                xv[u] = *(const float4*)&xp[(ts + u) * 256 + lane * 4];
            } else {
                aiv[u] = -1e30f; lfv[u] = 0.f; zkv[u] = 0.f;
                xv[u].x = xv[u].y = xv[u].z = xv[u].w = 0.f;
            }
        }
    }
    float S = 0.f, gsum = 0.f;
    float z0 = 0.f, z1 = 0.f, z2 = 0.f, z3 = 0.f;
    #pragma unroll
    for (int u = 7; u >= 0; --u) {
        float wv = __expf(aiv[u] + co0 + S) * zkv[u] * qb;
        S += lfv[u];
        float s = wv;
        s += __shfl_xor(s, 1, 64);
        s += __shfl_xor(s, 2, 64);
        s += __shfl_xor(s, 4, 64);
        s += __shfl_xor(s, 8, 64);
        s += __shfl_xor(s, 16, 64);
        s += __shfl_xor(s, 32, 64);
        gsum += s;
        z0 = fmaf(s, xv[u].x, z0);
        z1 = fmaf(s, xv[u].y, z1);
        z2 = fmaf(s, xv[u].z, z2);
        z3 = fmaf(s, xv[u].w, z3);
    }
    zred[w][lane * 4 + 0] = z0;
    zred[w][lane * 4 + 1] = z1;
    zred[w][lane * 4 + 2] = z2;
    zred[w][lane * 4 + 3] = z3;
    if (lane == 0) gred[w] = gsum;
    __syncthreads();
    if (tid < 256) {
        float s = zred[0][tid] + zred[1][tid] + zred[2][tid]
                + zred[3][tid] + zred[4][tid] + zred[5][tid];
        atomicAdd(&zf[tid], s);
    }
    if (tid == 0)
        atomicAdd(Gf, gred[0] + gred[1] + gred[2] + gred[3] + gred[4] + gred[5]);
}

// ---------- K6: wave-per-row GEMV finalize, grid 96 ----------
__global__ __launch_bounds__(256) void k6_out(const float* __restrict__ zf,
        const float* __restrict__ Gf,
        const float* __restrict__ Wv, const float* __restrict__ bv,
        const float* __restrict__ o, float* __restrict__ out) {
    int tid = threadIdx.x;
    int lane = tid & 63;
    int row = blockIdx.x * 4 + (tid >> 6);
    float Gv = Gf[0];
    float4 zv = *(const float4*)&zf[lane * 4];
    float4 wv = *(const float4*)&Wv[row * 256 + lane * 4];
    float acc = fmaf(zv.x, wv.x, fmaf(zv.y, wv.y, fmaf(zv.z, wv.z, zv.w * wv.w)));
    #pragma unroll
    for (int off = 32; off; off >>= 1) acc += __shfl_down(acc, off, 64);
    if (lane == 0)
        out[row] = o[row] * (acc + bv[row] * Gv) / fmaxf(fabsf(Gv), 1.0f);
}

extern "C" void kernel_launch(void* const* d_in, const int* in_sizes, int n_in,
                              void* d_out, int out_size, void* d_ws, size_t ws_size,
                              hipStream_t stream) {
    const float* x  = (const float*)d_in[0];
    const float* Wq = (const float*)d_in[1];  const float* bq = (const float*)d_in[2];
    const float* Wk = (const float*)d_in[3];  const float* bk = (const float*)d_in[4];
    const float* Wv = (const float*)d_in[5];  const float* bv = (const float*)d_in[6];
    const float* Wi = (const float*)d_in[7];  const float* bi = (const float*)d_in[8];
    const float* Wf = (const float*)d_in[9];  const float* bf = (const float*)d_in[10];
    const float* Wo = (const float*)d_in[11]; const float* bo = (const float*)d_in[12];
    const float* cw = (const float*)d_in[13]; const float* cb = (const float*)d_in[14];
    float* out = (float*)d_out;

    float* ws = (float*)d_ws;
    float* xp  = ws;                       // TP*F   = 525056
    float* zk  = xp  + TP * F;             // TP*H   = 787584
    float* ai  = zk  + TP * H;             // TP*H
    float* lf  = ai  + TP * H;             // TP*H
    float* cs  = lf  + TP * H;             // NCS*H  = 98688
    float* co  = cs  + NCS * H;            // NCS*H
    float* qv  = co  + NCS * H;            // H
    float* ov  = qv  + H;                  // H
    float* zf  = ov  + H;                  // F (z accumulator)
    float* Gf  = zf  + F;                  // 1 (+pad)

    hipMemsetAsync((void*)zf, 0, (F + 4) * sizeof(float), stream);
    k1_conv<<<(TP + 3) / 4, 256, 0, stream>>>(x, cw, cb, xp);
    k2b_qo<<<96, 256, 0, stream>>>(xp, Wq, bq, Wo, bo, qv, ov);
    k2_proj<<<dim3(NT2, 6), 256, 0, stream>>>(xp, Wk, bk, Wi, bi, Wf, bf, zk, ai, lf, cs);
    k3b_scan<<<6, 64, 0, stream>>>(cs, co);
    k3_fused<<<NC3, 384, 0, stream>>>(ai, lf, zk, co, qv, xp, zf, Gf);
    k6_out<<<96, 256, 0, stream>>>(zf, Gf, Wv, bv, ov, out);
}